// Round 2
// baseline (191.038 us; speedup 1.0000x reference)
//
#include <hip/hip_runtime.h>

#define W_     1024
#define H_     1024
#define NIMG   16
#define HS     32            // output rows per block strip
#define NTHR   128           // threads per block (2 waves)
#define PAD    4             // 9//2
#define CS_N   (W_ + 2*PAD)  // 1032 padded-column coords
#define EPS_   1e-5f
#define VS_LD  1160          // swz(1031)+1 = 1159+1

__device__ __forceinline__ int swz(int cs) { return cs + (cs >> 3); }

__global__ __launch_bounds__(NTHR) void ncc_main(const float* __restrict__ Iall,
                                                 const float* __restrict__ Jall,
                                                 float* __restrict__ acc)
{
    const int bx    = blockIdx.x;
    const int img   = bx >> 5;          // 32 strips per image
    const int strip = bx & 31;
    const int r0    = strip * HS;
    const int t     = threadIdx.x;

    const float* __restrict__ Ib = Iall + (size_t)img * (W_ * H_);
    const float* __restrict__ Jb = Jall + (size_t)img * (W_ * H_);

    __shared__ float vs[5][VS_LD];

    // zero-pad edge columns (cs in [0,4) and [1028,1032)) — written once, never overwritten
    if (t < 2 * PAD) {
        int cs = (t < PAD) ? t : (CS_N - 2 * PAD + t);
        #pragma unroll
        for (int ch = 0; ch < 5; ++ch) vs[ch][swz(cs)] = 0.0f;
    }

    // vertical running box sums, 8 strided columns per thread
    float sI[8], sJ[8], sII[8], sJJ[8], sIJ[8];
    #pragma unroll
    for (int k = 0; k < 8; ++k) { sI[k]=0.f; sJ[k]=0.f; sII[k]=0.f; sJJ[k]=0.f; sIJ[k]=0.f; }

    // warm-up: rows r0-4 .. r0+3
    for (int q = r0 - PAD; q < r0 + PAD; ++q) {
        if (q >= 0) {
            #pragma unroll
            for (int k = 0; k < 8; ++k) {
                const int c = t + k * NTHR;
                const float a = Ib[q * W_ + c];
                const float b = Jb[q * W_ + c];
                sI[k]+=a; sJ[k]+=b; sII[k]+=a*a; sJJ[k]+=b*b; sIJ[k]+=a*b;
            }
        }
    }
    __syncthreads();

    float accum = 0.0f;
    const float inv81 = 1.0f / 81.0f;

    for (int r = r0; r < r0 + HS; ++r) {
        // enter row r+4
        const int qe = r + PAD;
        if (qe < H_) {
            #pragma unroll
            for (int k = 0; k < 8; ++k) {
                const int c = t + k * NTHR;
                const float a = Ib[qe * W_ + c];
                const float b = Jb[qe * W_ + c];
                sI[k]+=a; sJ[k]+=b; sII[k]+=a*a; sJJ[k]+=b*b; sIJ[k]+=a*b;
            }
        }
        // publish vertical sums (swizzled; lanes contiguous -> ~conflict-free)
        #pragma unroll
        for (int k = 0; k < 8; ++k) {
            const int idx = swz(t + k * NTHR + PAD);
            vs[0][idx] = sI[k];
            vs[1][idx] = sJ[k];
            vs[2][idx] = sII[k];
            vs[3][idx] = sJJ[k];
            vs[4][idx] = sIJ[k];
        }
        __syncthreads();

        // horizontal: thread owns cols 8t..8t+7; window covers cs = 8t..8t+15
        float h[5][8];
        {
            const int base = t * 8;
            #pragma unroll
            for (int ch = 0; ch < 5; ++ch) {
                float w[16];
                #pragma unroll
                for (int x = 0; x < 16; ++x) w[x] = vs[ch][swz(base + x)];
                float s = 0.f;
                #pragma unroll
                for (int x = 0; x < 9; ++x) s += w[x];
                h[ch][0] = s;
                #pragma unroll
                for (int c = 1; c < 8; ++c) { s += w[c + 8] - w[c - 1]; h[ch][c] = s; }
            }
        }
        #pragma unroll
        for (int c = 0; c < 8; ++c) {
            const float SI = h[0][c], SJ = h[1][c];
            const float SII = h[2][c], SJJ = h[3][c], SIJ = h[4][c];
            const float cross = SIJ - SI * SJ * inv81;
            const float iv    = SII - SI * SI * inv81;
            const float jv    = SJJ - SJ * SJ * inv81;
            accum += cross * cross / (iv * jv + EPS_);
        }
        __syncthreads();

        // leave row r-4 (re-read; should be L2-resident — read 9 rows ago)
        const int ql = r - PAD;
        if (ql >= 0 && r + 1 < r0 + HS) {
            #pragma unroll
            for (int k = 0; k < 8; ++k) {
                const int c = t + k * NTHR;
                const float a = Ib[ql * W_ + c];
                const float b = Jb[ql * W_ + c];
                sI[k]-=a; sJ[k]-=b; sII[k]-=a*a; sJJ[k]-=b*b; sIJ[k]-=a*b;
            }
        }
    }

    // block reduction: wave shuffle + one atomic per wave
    #pragma unroll
    for (int off = 32; off > 0; off >>= 1) accum += __shfl_down(accum, off);
    if ((t & 63) == 0) atomicAdd(acc, accum);
}

__global__ void ncc_finalize(const float* __restrict__ acc, float* __restrict__ out)
{
    out[0] = 1.0f - acc[0] * (1.0f / (float)((size_t)NIMG * W_ * H_));
}

extern "C" void kernel_launch(void* const* d_in, const int* in_sizes, int n_in,
                              void* d_out, int out_size, void* d_ws, size_t ws_size,
                              hipStream_t stream)
{
    const float* I = (const float*)d_in[0];
    const float* J = (const float*)d_in[1];
    float* acc = (float*)d_ws;

    hipMemsetAsync(acc, 0, sizeof(float), stream);
    ncc_main<<<NIMG * (H_ / HS), NTHR, 0, stream>>>(I, J, acc);
    ncc_finalize<<<1, 1, 0, stream>>>(acc, (float*)d_out);
}

// Round 3
// 185.468 us; speedup vs baseline: 1.0300x; 1.0300x over previous
//
#include <hip/hip_runtime.h>

#define W_     1024
#define H_     1024
#define NIMG   16
#define HS     16            // output rows per block strip
#define NTHR   128           // threads per block (2 waves)
#define PAD    4             // 9//2
#define EPS_   1e-5f
// 128B-granular pad swizzle: insert 4 dwords every 32 -> lane-group bank
// stride becomes 36 = 4 (mod 32): conflict-free b128 reads/writes.
__device__ __forceinline__ int f_(int cs) { return cs + ((cs >> 5) << 2); }
#define VS_LD  1160          // f_(1031)+1 = 1160

__global__ __launch_bounds__(NTHR, 2) void ncc_main(const float* __restrict__ Iall,
                                                    const float* __restrict__ Jall,
                                                    float* __restrict__ acc)
{
    const int bx    = blockIdx.x;
    const int img   = bx >> 6;          // 64 strips per image
    const int strip = bx & 63;
    const int r0    = strip * HS;
    const int t     = threadIdx.x;
    const int c0    = t * 8;            // 8 contiguous cols per thread

    const float* __restrict__ Ib = Iall + (size_t)img * (W_ * H_);
    const float* __restrict__ Jb = Jall + (size_t)img * (W_ * H_);

    __shared__ float vs[5][VS_LD];

    // zero pad columns cs in [0,4) and [1028,1032)
    if (t < 2 * PAD) {
        const int cs = (t < PAD) ? t : (1024 + t);
        #pragma unroll
        for (int ch = 0; ch < 5; ++ch) vs[ch][f_(cs)] = 0.0f;
    }

    // vertical running box sums for 8 contiguous columns
    float sI[8], sJ[8], sII[8], sJJ[8], sIJ[8];
    #pragma unroll
    for (int k = 0; k < 8; ++k) { sI[k]=0.f; sJ[k]=0.f; sII[k]=0.f; sJJ[k]=0.f; sIJ[k]=0.f; }

    // warm-up rows r0-4 .. r0+3
    for (int q = r0 - PAD; q < r0 + PAD; ++q) {
        if (q >= 0) {
            const float4 a0 = *reinterpret_cast<const float4*>(Ib + (size_t)q * W_ + c0);
            const float4 a1 = *reinterpret_cast<const float4*>(Ib + (size_t)q * W_ + c0 + 4);
            const float4 b0 = *reinterpret_cast<const float4*>(Jb + (size_t)q * W_ + c0);
            const float4 b1 = *reinterpret_cast<const float4*>(Jb + (size_t)q * W_ + c0 + 4);
            const float av[8] = {a0.x,a0.y,a0.z,a0.w,a1.x,a1.y,a1.z,a1.w};
            const float bv[8] = {b0.x,b0.y,b0.z,b0.w,b1.x,b1.y,b1.z,b1.w};
            #pragma unroll
            for (int k = 0; k < 8; ++k) {
                sI[k]+=av[k]; sJ[k]+=bv[k];
                sII[k]=__builtin_fmaf(av[k],av[k],sII[k]);
                sJJ[k]=__builtin_fmaf(bv[k],bv[k],sJJ[k]);
                sIJ[k]=__builtin_fmaf(av[k],bv[k],sIJ[k]);
            }
        }
    }
    __syncthreads();

    float accum = 0.0f;
    const float inv81 = 1.0f / 81.0f;

    // precomputed LDS dword offsets (swizzled, all b128-contiguous)
    const int wi0 = f_(PAD + c0), wi1 = f_(PAD + c0 + 4);
    const int ri0 = f_(c0), ri1 = f_(c0 + 4), ri2 = f_(c0 + 8), ri3 = f_(c0 + 12);

    for (int r = r0; r < r0 + HS; ++r) {
        // enter row r+4
        const int qe = r + PAD;
        if (qe < H_) {
            const float4 a0 = *reinterpret_cast<const float4*>(Ib + (size_t)qe * W_ + c0);
            const float4 a1 = *reinterpret_cast<const float4*>(Ib + (size_t)qe * W_ + c0 + 4);
            const float4 b0 = *reinterpret_cast<const float4*>(Jb + (size_t)qe * W_ + c0);
            const float4 b1 = *reinterpret_cast<const float4*>(Jb + (size_t)qe * W_ + c0 + 4);
            const float av[8] = {a0.x,a0.y,a0.z,a0.w,a1.x,a1.y,a1.z,a1.w};
            const float bv[8] = {b0.x,b0.y,b0.z,b0.w,b1.x,b1.y,b1.z,b1.w};
            #pragma unroll
            for (int k = 0; k < 8; ++k) {
                sI[k]+=av[k]; sJ[k]+=bv[k];
                sII[k]=__builtin_fmaf(av[k],av[k],sII[k]);
                sJJ[k]=__builtin_fmaf(bv[k],bv[k],sJJ[k]);
                sIJ[k]=__builtin_fmaf(av[k],bv[k],sIJ[k]);
            }
        }
        // publish vertical sums: 2x ds_write_b128 per channel
        {
            float* p;
            p = &vs[0][0];
            *reinterpret_cast<float4*>(p+wi0) = make_float4(sI[0],sI[1],sI[2],sI[3]);
            *reinterpret_cast<float4*>(p+wi1) = make_float4(sI[4],sI[5],sI[6],sI[7]);
            p = &vs[1][0];
            *reinterpret_cast<float4*>(p+wi0) = make_float4(sJ[0],sJ[1],sJ[2],sJ[3]);
            *reinterpret_cast<float4*>(p+wi1) = make_float4(sJ[4],sJ[5],sJ[6],sJ[7]);
            p = &vs[2][0];
            *reinterpret_cast<float4*>(p+wi0) = make_float4(sII[0],sII[1],sII[2],sII[3]);
            *reinterpret_cast<float4*>(p+wi1) = make_float4(sII[4],sII[5],sII[6],sII[7]);
            p = &vs[3][0];
            *reinterpret_cast<float4*>(p+wi0) = make_float4(sJJ[0],sJJ[1],sJJ[2],sJJ[3]);
            *reinterpret_cast<float4*>(p+wi1) = make_float4(sJJ[4],sJJ[5],sJJ[6],sJJ[7]);
            p = &vs[4][0];
            *reinterpret_cast<float4*>(p+wi0) = make_float4(sIJ[0],sIJ[1],sIJ[2],sIJ[3]);
            *reinterpret_cast<float4*>(p+wi1) = make_float4(sIJ[4],sIJ[5],sIJ[6],sIJ[7]);
        }
        __syncthreads();

        // horizontal: window for output col c is vs[cs=c .. c+8]; thread t
        // needs cs in [8t, 8t+16): 4x ds_read_b128 per channel
        float h[5][8];
        #pragma unroll
        for (int ch = 0; ch < 5; ++ch) {
            const float* p = &vs[ch][0];
            const float4 w0 = *reinterpret_cast<const float4*>(p + ri0);
            const float4 w1 = *reinterpret_cast<const float4*>(p + ri1);
            const float4 w2 = *reinterpret_cast<const float4*>(p + ri2);
            const float4 w3 = *reinterpret_cast<const float4*>(p + ri3);
            const float w[16] = {w0.x,w0.y,w0.z,w0.w, w1.x,w1.y,w1.z,w1.w,
                                 w2.x,w2.y,w2.z,w2.w, w3.x,w3.y,w3.z,w3.w};
            float s = 0.f;
            #pragma unroll
            for (int x = 0; x < 9; ++x) s += w[x];
            h[ch][0] = s;
            #pragma unroll
            for (int c = 1; c < 8; ++c) { s += w[c + 8] - w[c - 1]; h[ch][c] = s; }
        }
        #pragma unroll
        for (int c = 0; c < 8; ++c) {
            const float SI = h[0][c], SJ = h[1][c];
            const float SII = h[2][c], SJJ = h[3][c], SIJ = h[4][c];
            const float cross = __builtin_fmaf(-SI * SJ, inv81, SIJ);
            const float iv    = __builtin_fmaf(-SI * SI, inv81, SII);
            const float jv    = __builtin_fmaf(-SJ * SJ, inv81, SJJ);
            accum = __builtin_fmaf(cross * cross,
                                   __builtin_amdgcn_rcpf(__builtin_fmaf(iv, jv, EPS_)),
                                   accum);
        }
        __syncthreads();

        // leave row r-4 (L2-resident re-read)
        const int ql = r - PAD;
        if (ql >= 0 && r + 1 < r0 + HS) {
            const float4 a0 = *reinterpret_cast<const float4*>(Ib + (size_t)ql * W_ + c0);
            const float4 a1 = *reinterpret_cast<const float4*>(Ib + (size_t)ql * W_ + c0 + 4);
            const float4 b0 = *reinterpret_cast<const float4*>(Jb + (size_t)ql * W_ + c0);
            const float4 b1 = *reinterpret_cast<const float4*>(Jb + (size_t)ql * W_ + c0 + 4);
            const float av[8] = {a0.x,a0.y,a0.z,a0.w,a1.x,a1.y,a1.z,a1.w};
            const float bv[8] = {b0.x,b0.y,b0.z,b0.w,b1.x,b1.y,b1.z,b1.w};
            #pragma unroll
            for (int k = 0; k < 8; ++k) {
                sI[k]-=av[k]; sJ[k]-=bv[k];
                sII[k]=__builtin_fmaf(-av[k],av[k],sII[k]);
                sJJ[k]=__builtin_fmaf(-bv[k],bv[k],sJJ[k]);
                sIJ[k]=__builtin_fmaf(-av[k],bv[k],sIJ[k]);
            }
        }
    }

    // block reduction: wave shuffle + one atomic per wave
    #pragma unroll
    for (int off = 32; off > 0; off >>= 1) accum += __shfl_down(accum, off);
    if ((t & 63) == 0) atomicAdd(acc, accum);
}

__global__ void ncc_finalize(const float* __restrict__ acc, float* __restrict__ out)
{
    out[0] = 1.0f - acc[0] * (1.0f / (float)((size_t)NIMG * W_ * H_));
}

extern "C" void kernel_launch(void* const* d_in, const int* in_sizes, int n_in,
                              void* d_out, int out_size, void* d_ws, size_t ws_size,
                              hipStream_t stream)
{
    const float* I = (const float*)d_in[0];
    const float* J = (const float*)d_in[1];
    float* acc = (float*)d_ws;

    hipMemsetAsync(acc, 0, sizeof(float), stream);
    ncc_main<<<NIMG * (H_ / HS), NTHR, 0, stream>>>(I, J, acc);
    ncc_finalize<<<1, 1, 0, stream>>>(acc, (float*)d_out);
}